// Round 7
// baseline (55562.976 us; speedup 1.0000x reference)
//
#include <hip/hip_runtime.h>
#include <hip/hip_bf16.h>

// ---------------------------------------------------------------------------
// FULL FLOAT64 pipeline (rounds 4/5: state + activations must be f64).
// Round-21: r18's "race" re-diagnosed — its absmax 0.0918 was IDENTICAL to
// r19's, i.e. the deterministic wr-decode bug (px 64-127 never written),
// NOT a pipeline race. The write-early raw-barrier pipeline was never
// falsified. This round: r16 grids + correct wr=(wave>>1)*32 + the 2-deep
// write-early pipeline. Per chunk: ds_write(st_hold -> buf^1) [vmcnt dep
// one chunk old ~ free], MFMA(cur) under setprio, issue loads for ch+2,
// then lgkmcnt(0) + raw s_barrier + sched_barrier(0) — global loads stay
// in flight across the barrier (kills the __syncthreads vmcnt(0) drain,
// the m97 stall = r16's ~39% MFMA idle). MFMA k-order unchanged ->
// numerics identical to r16 (absmax 0.001953125). Persistence dropped
// (r20: wash, +35% FETCH).
//
//   job j = img * NSTRIP + s ; img = j >> ns_shift ; r0 = (j & (NSTRIP-1))*R
//   h0 slot: [(R+8) rows][256][8] f64 ; h1: [(R+4)][256][256] ;
//   h2: [(R+2)][256][256] ; h3 = h1 alias
//   packed weights f64: Wp[k*256+oc], k = tap*CIN+cin (tap-major)
//   xpA/xpB: [NPIX] f64 ping-pong state; d_out: [NPIX] f32
// ---------------------------------------------------------------------------

#define NPIX (4 * 256 * 256)

typedef double v4d __attribute__((ext_vector_type(4)));

#define PIPE_BARRIER() do {                                   \
    asm volatile("s_waitcnt lgkmcnt(0)" ::: "memory");        \
    __builtin_amdgcn_s_barrier();                             \
    __builtin_amdgcn_sched_barrier(0);                        \
} while (0)

// ---------------- one-wave f64-MFMA C/D-layout probe -----------------------
__global__ __launch_bounds__(64) void probe_mode(int* __restrict__ modep)
{
    int lr = threadIdx.x & 15;
    v4d p1 = {}, p2 = {};
    p1 = __builtin_amdgcn_mfma_f64_16x16x4f64((double)lr, 1.0, p1, 0, 0, 0);
    p2 = __builtin_amdgcn_mfma_f64_16x16x4f64(1.0, (double)lr, p2, 0, 0, 0);
    double v1 = __shfl(p1[0], 16);
    double v2 = __shfl(p2[0], 16);
    if (threadIdx.x == 0)
        *modep = (v1 == 16.0) ? 0 : (v1 == 4.0) ? 1 : (v2 == 16.0) ? 2 : 3;
}

// ---------------------- x (f32) -> xp (f64) init ---------------------------
__global__ __launch_bounds__(256) void xinit_kernel(
    const float* __restrict__ x, double* __restrict__ xp64)
{
    int p = blockIdx.x * 256 + threadIdx.x;
    xp64[p] = (double)x[p];
}

// ------------------- stencil features, job-sliced --------------------------
__global__ __launch_bounds__(256) void stencil_strip(
    const float* __restrict__ x, const double* __restrict__ xp,
    double* __restrict__ h0, size_t h0_is,
    int job0, int ns_shift, int R)
{
    int slot = blockIdx.y;
    int j = job0 + slot;
    int img = j >> ns_shift;
    int r0 = (j & ((1 << ns_shift) - 1)) * R;
    int pbase = img << 16;
    int y = (r0 - 4 + blockIdx.x) & 255;
    int col = threadIdx.x;
    double q[8];
    int s = 0, idx = 0;
    #pragma unroll
    for (int i = -1; i <= 1; ++i)
        #pragma unroll
        for (int jj = -1; jj <= 1; ++jj) {
            if (i == 0 && jj == 0) continue;
            int ys = (y - i) & 255, xs = (col - jj) & 255;
            double v = xp[pbase + ((ys << 8) | xs)];
            q[idx++] = v;
            s += (v > 0.5) ? 1 : 0;
        }
    double c = xp[pbase + ((y << 8) | col)];
    bool alive = c > 0.5;
    bool binnext = (s == 3) || (alive && s == 2);
    double c0 = 1.0, c1 = 0.0, c2 = 0.0, c3 = 0.0;   // count DP, ref order
    #pragma unroll
    for (int k = 0; k < 8; ++k) {
        double qq = q[k], r = 1.0 - qq;
        c3 = c3 * r + c2 * qq;
        c2 = c2 * r + c1 * qq;
        c1 = c1 * r + c0 * qq;
        c0 = c0 * r;
    }
    double xpred = c3 + c2 * c;
    double* o = h0 + slot * h0_is + ((size_t)blockIdx.x * 256 + col) * 8;
    o[0] = (double)x[pbase + ((y << 8) | col)];
    o[1] = c;
    o[2] = alive ? 1.0 : 0.0;
    o[3] = xpred;
    o[4] = binnext ? 1.0 : 0.0;
    o[5] = 0.0; o[6] = 0.0; o[7] = 0.0;
}

// ------------- generic f64 MFMA conv GEMM (conv1/conv3) --------------------
// Tile 128px x 64oc; 8 waves, each a 32x32 quadrant (acc[2][2]).
// 2-deep write-early pipeline, raw s_barrier (no vmcnt drain).
template<int CIN, int TK, int KH, int KW>
__global__ __launch_bounds__(512, 6) void conv_gemm(
    const double* __restrict__ A, size_t a_is,
    const double* __restrict__ Wp,
    const float* __restrict__ bias,
    double* __restrict__ O, size_t o_is,
    int delta, const int* __restrict__ modep)
{
    constexpr int PW = KW / 2, PH = KH / 2;
    constexpr int CHUNKS = CIN / TK;
    constexpr int NCH = KH * KW * CHUNKS;
    constexpr int LPP = TK / 2;            // double2 (ch-pairs) per px
    constexpr int NA = 128 * LPP;          // A double2 tasks per chunk
    constexpr int NW = TK * 32;            // W double2 tasks per chunk
    constexpr int NT = NA + NW;
    constexpr int TPT = (NT + 511) / 512;  // staged double2 per thread

    __shared__ double Asmem[2][TK][130];   // [buf][k][px]
    __shared__ double Wsmem[2][TK][66];    // [buf][k][oc]

    const double* Ai = A + blockIdx.z * a_is;
    double* Oi = O + blockIdx.z * o_is;
    const int mode = *modep;

    const int tid = threadIdx.x;
    const int pm0 = blockIdx.x * 128;      // 128 | 256 -> row-aligned tiles
    const int on0 = blockIdx.y * 64;
    const int yl0 = pm0 >> 8;              // constant per block
    const int c0l = pm0 & 255;
    const int wave = tid >> 6, lane = tid & 63;
    const int lq = lane >> 4, lr = lane & 15;
    const int wr = (wave >> 1) * 32;       // {0,32,64,96}  (correct decode)
    const int wc = (wave & 1) * 32;        // {0,32}

    v4d acc[2][2] = {};
    double2 stA[TPT], stB[TPT];

    auto load_tasks = [&](int ch, double2 (&st)[TPT]) {
        int tap = ch / CHUNKS, cc = ch - tap * CHUNKS;
        int dy = tap / KW - PH, dx = tap % KW - PW;
        int c0 = cc * TK;
        int kglob = tap * CIN + c0;
        int srow = yl0 + dy + delta;
        #pragma unroll
        for (int i = 0; i < TPT; ++i) {
            int u = tid + i * 512;
            if (NT % 512 == 0 || u < NT) {
                if (u < NA) {
                    int px = u / LPP, pp = u % LPP;
                    int xs = (c0l + px + dx) & 255;
                    st[i] = *(const double2*)(
                        Ai + (size_t)((srow << 8) | xs) * CIN + c0 + pp * 2);
                } else {
                    int u2 = u - NA;
                    int row = u2 >> 5, cp = (u2 & 31) << 1;
                    st[i] = *(const double2*)&Wp[
                        (size_t)(kglob + row) * 256 + on0 + cp];
                }
            }
        }
    };
    auto write_tasks = [&](int buf, double2 (&st)[TPT]) {
        #pragma unroll
        for (int i = 0; i < TPT; ++i) {
            int u = tid + i * 512;
            if (NT % 512 == 0 || u < NT) {
                if (u < NA) {
                    int px = u / LPP, pp = u % LPP;
                    Asmem[buf][pp * 2 + 0][px] = st[i].x;
                    Asmem[buf][pp * 2 + 1][px] = st[i].y;
                } else {
                    int u2 = u - NA;
                    int row = u2 >> 5, cp = (u2 & 31) << 1;
                    *(double2*)&Wsmem[buf][row][cp] = st[i];
                }
            }
        }
    };
    auto mfma_step = [&](int cur) {
        __builtin_amdgcn_s_setprio(1);
        #pragma unroll
        for (int k0 = 0; k0 < TK / 4; ++k0) {
            const int kk = k0 * 4 + lq;
            double a[2], b[2];
            a[0] = Asmem[cur][kk][wr + lr];
            a[1] = Asmem[cur][kk][wr + 16 + lr];
            b[0] = Wsmem[cur][kk][wc + lr];
            b[1] = Wsmem[cur][kk][wc + 16 + lr];
            #pragma unroll
            for (int rt = 0; rt < 2; ++rt)
                #pragma unroll
                for (int ct = 0; ct < 2; ++ct)
                    acc[rt][ct] = __builtin_amdgcn_mfma_f64_16x16x4f64(
                        a[rt], b[ct], acc[rt][ct], 0, 0, 0);
        }
        __builtin_amdgcn_s_setprio(0);
    };

    // Prologue: buf0 <- chunk0; stB <- chunk1 (stays in flight across barrier)
    load_tasks(0, stA);
    write_tasks(0, stA);
    load_tasks(1, stB);
    PIPE_BARRIER();

    for (int ch = 0; ch < NCH; ch += 2) {
        {   // even chunk: reads buf0; stB holds chunk ch+1
            if (ch + 1 < NCH) write_tasks(1, stB);
            mfma_step(0);
            if (ch + 2 < NCH) load_tasks(ch + 2, stA);
            PIPE_BARRIER();
        }
        if (ch + 1 < NCH) {  // odd chunk: reads buf1; stA holds chunk ch+2
            if (ch + 2 < NCH) write_tasks(0, stA);
            mfma_step(1);
            if (ch + 3 < NCH) load_tasks(ch + 3, stB);
            PIPE_BARRIER();
        }
    }

    #pragma unroll
    for (int rt = 0; rt < 2; ++rt)
        #pragma unroll
        for (int ct = 0; ct < 2; ++ct)
            #pragma unroll
            for (int i = 0; i < 4; ++i) {
                int hq = lq * 4 + i, hi = i * 4 + lq;
                int rl = (mode == 0) ? hq : (mode == 1) ? hi : lr;
                int cl = (mode <= 1) ? lr : (mode == 2) ? hq : hi;
                int px = pm0 + wr + rt * 16 + rl;
                int oc = on0 + wc + ct * 16 + cl;
                Oi[(size_t)px * 256 + oc] =
                    fmax(acc[rt][ct][i] + (double)bias[oc], 0.0);
            }
}

// ------------- conv2-specialized GEMM: 3x3, 256cin, dy-grouped -------------
// Chunk = (dy, cc8): A[8][130] (dx-halo over 128px), W 24 rows x 64 oc.
// 8 waves x 24 MFMA/chunk; NCH = 96. 2-deep write-early pipeline.
__global__ __launch_bounds__(512, 6) void conv2_gemm(
    const double* __restrict__ A, size_t a_is,    // h1 [R+4][256][256]
    const double* __restrict__ Wp,                // [2304, 256]
    const float* __restrict__ bias,
    double* __restrict__ O, size_t o_is,          // h2 [R+2][256][256]
    const int* __restrict__ modep)
{
    __shared__ double Asmem[2][8][130];    // [buf][k][px(-1..128)]
    __shared__ double Wsmem[2][24][66];    // [buf][dx*8+k][oc]
    constexpr int NA = 520;                // 130 px * 4 ch-pairs
    constexpr int NT = 1288;               // + 24*32 W tasks
    constexpr int TPT = 3;                 // ceil(1288/512)
    constexpr int NCH = 96;

    const double* Ai = A + blockIdx.z * a_is;
    double* Oi = O + blockIdx.z * o_is;
    const int mode = *modep;

    const int tid = threadIdx.x;
    const int pm0 = blockIdx.x * 128;
    const int on0 = blockIdx.y * 64;       // grid.y = 4
    const int yrow = pm0 >> 8;             // h2-local row (tile spans 1/2 row)
    const int col0 = pm0 & 255;
    const int wave = tid >> 6, lane = tid & 63;
    const int lq = lane >> 4, lr = lane & 15;
    const int wr = (wave >> 1) * 32;       // {0,32,64,96}  (correct decode)
    const int wc = (wave & 1) * 32;        // {0,32}

    v4d acc[2][2] = {};
    double2 stA[TPT], stB[TPT];

    auto load_tasks = [&](int ch, double2 (&st)[TPT]) {
        int dy = ch >> 5;                  // [0,3)
        int cc = ch & 31;
        int c0 = cc * 8;
        int srow = yrow + dy;              // h1 row (delta=1: yl+dy-1+1)
        #pragma unroll
        for (int i = 0; i < TPT; ++i) {
            int u = tid + i * 512;
            if (u < NT) {
                if (u < NA) {
                    int px = u >> 2, pp = u & 3;
                    int xs = (col0 - 1 + px) & 255;
                    st[i] = *(const double2*)(
                        Ai + (size_t)((srow << 8) | xs) * 256 + c0 + pp * 2);
                } else {
                    int u2 = u - NA;
                    int row = u2 >> 5, cp = (u2 & 31) << 1;
                    int tap = dy * 3 + (row >> 3);
                    int k = tap * 256 + c0 + (row & 7);
                    st[i] = *(const double2*)&Wp[(size_t)k * 256 + on0 + cp];
                }
            }
        }
    };
    auto write_tasks = [&](int buf, double2 (&st)[TPT]) {
        #pragma unroll
        for (int i = 0; i < TPT; ++i) {
            int u = tid + i * 512;
            if (u < NT) {
                if (u < NA) {
                    int px = u >> 2, pp = u & 3;
                    Asmem[buf][pp * 2 + 0][px] = st[i].x;
                    Asmem[buf][pp * 2 + 1][px] = st[i].y;
                } else {
                    int u2 = u - NA;
                    int row = u2 >> 5, cp = (u2 & 31) << 1;
                    *(double2*)&Wsmem[buf][row][cp] = st[i];
                }
            }
        }
    };
    auto mfma_step = [&](int cur) {
        __builtin_amdgcn_s_setprio(1);
        #pragma unroll
        for (int dx = 0; dx < 3; ++dx)
            #pragma unroll
            for (int k0 = 0; k0 < 2; ++k0) {
                const int kA = k0 * 4 + lq;
                const int kW = dx * 8 + k0 * 4 + lq;
                double a[2], b[2];
                a[0] = Asmem[cur][kA][dx + wr + lr];
                a[1] = Asmem[cur][kA][dx + wr + 16 + lr];
                b[0] = Wsmem[cur][kW][wc + lr];
                b[1] = Wsmem[cur][kW][wc + 16 + lr];
                #pragma unroll
                for (int rt = 0; rt < 2; ++rt)
                    #pragma unroll
                    for (int ct = 0; ct < 2; ++ct)
                        acc[rt][ct] = __builtin_amdgcn_mfma_f64_16x16x4f64(
                            a[rt], b[ct], acc[rt][ct], 0, 0, 0);
            }
        __builtin_amdgcn_s_setprio(0);
    };

    // Prologue: buf0 <- chunk0; stB <- chunk1 (stays in flight across barrier)
    load_tasks(0, stA);
    write_tasks(0, stA);
    load_tasks(1, stB);
    PIPE_BARRIER();

    for (int ch = 0; ch < NCH; ch += 2) {
        {   // even chunk
            if (ch + 1 < NCH) write_tasks(1, stB);
            mfma_step(0);
            if (ch + 2 < NCH) load_tasks(ch + 2, stA);
            PIPE_BARRIER();
        }
        {   // odd chunk (NCH even -> always valid)
            if (ch + 2 < NCH) write_tasks(0, stA);
            mfma_step(1);
            if (ch + 3 < NCH) load_tasks(ch + 3, stB);
            PIPE_BARRIER();
        }
    }

    #pragma unroll
    for (int rt = 0; rt < 2; ++rt)
        #pragma unroll
        for (int ct = 0; ct < 2; ++ct)
            #pragma unroll
            for (int i = 0; i < 4; ++i) {
                int hq = lq * 4 + i, hi = i * 4 + lq;
                int rl = (mode == 0) ? hq : (mode == 1) ? hi : lr;
                int cl = (mode <= 1) ? lr : (mode == 2) ? hq : hi;
                int px = pm0 + wr + rt * 16 + rl;
                int oc = on0 + wc + ct * 16 + cl;
                Oi[(size_t)px * 256 + oc] =
                    fmax(acc[rt][ct][i] + (double)bias[oc], 0.0);
            }
}

// --------------- conv4: 256->1, 3x3, + sigmoid, wave-per-pixel -------------
__global__ __launch_bounds__(256) void conv4_sig(
    const double* __restrict__ H3, size_t h3_is,
    const float* __restrict__ w4, const float* __restrict__ b4,
    float* __restrict__ out, double* __restrict__ xp_new,
    int job0, int ns_shift, int R)
{
    __shared__ double w4s[2304];     // w4[cin][kh][kw] f64
    int tid = threadIdx.x;
    for (int i = tid; i < 2304; i += 256) w4s[i] = (double)w4[i];
    __syncthreads();
    int slot = blockIdx.y;
    int j = job0 + slot;
    int img = j >> ns_shift;
    int r0 = (j & ((1 << ns_shift) - 1)) * R;
    const double* H3i = H3 + slot * h3_is;
    int pbase = img << 16;
    int lane = tid & 63, wv = tid >> 6;
    int p0 = blockIdx.x * 64 + wv * 16;
    for (int pi = 0; pi < 16; ++pi) {
        int pl = p0 + pi;
        int yl = pl >> 8, col = pl & 255;
        double acc = 0.0;
        #pragma unroll
        for (int tap = 0; tap < 9; ++tap) {
            int row = yl + tap / 3 - 1 + 1;                 // delta = 1
            int xs = (col + tap % 3 - 1) & 255;
            const double* src = H3i + (size_t)((row << 8) | xs) * 256;
            #pragma unroll
            for (int jj = 0; jj < 4; ++jj) {
                int c = lane + 64 * jj;
                acc = fma(src[c], w4s[c * 9 + tap], acc);
            }
        }
        #pragma unroll
        for (int off = 32; off; off >>= 1) acc += __shfl_xor(acc, off, 64);
        if (lane == 0) {
            double v = acc + (double)b4[0];
            double s = 1.0 / (1.0 + exp(-v));
            int p = pbase + (((r0 + yl) << 8) | col);
            out[p] = (float)s;
            xp_new[p] = s;
        }
    }
}

// ----------------------------- weight repacks (f32 -> f64) -----------------
__global__ void repack_w1(const float* __restrict__ w1, double* __restrict__ W1p) {
    int t = blockIdx.x * 256 + threadIdx.x;           // [(tap*8+cin)*256+oc]
    if (t >= 25 * 8 * 256) return;
    int oc = t & 255, cin = (t >> 8) & 7, tap = t >> 11;
    W1p[t] = (cin < 5) ? (double)w1[oc * 125 + cin * 25 + tap] : 0.0;
}
__global__ void repack_w2(const float* __restrict__ w2, double* __restrict__ W2p) {
    int t = blockIdx.x * 256 + threadIdx.x;           // [(tap*256+cin)*256+oc]
    if (t >= 9 * 256 * 256) return;
    int oc = t & 255, cin = (t >> 8) & 255, tap = t >> 16;
    W2p[t] = (double)w2[((oc << 8) | cin) * 9 + tap];
}
__global__ void repack_w3(const float* __restrict__ w3, double* __restrict__ W3p) {
    int t = blockIdx.x * 256 + threadIdx.x;           // [cin*256+oc]
    if (t >= 256 * 256) return;
    int oc = t & 255, cin = t >> 8;
    W3p[t] = (double)w3[oc * 256 + cin];
}

// ------------------------------- launcher ----------------------------------
extern "C" void kernel_launch(void* const* d_in, const int* in_sizes, int n_in,
                              void* d_out, int out_size, void* d_ws, size_t ws_size,
                              hipStream_t stream)
{
    const float* x  = (const float*)d_in[0];
    const float* w1 = (const float*)d_in[1];
    const float* b1 = (const float*)d_in[2];
    const float* w2 = (const float*)d_in[3];
    const float* b2 = (const float*)d_in[4];
    const float* w3 = (const float*)d_in[5];
    const float* b3 = (const float*)d_in[6];
    const float* w4 = (const float*)d_in[7];
    const float* b4 = (const float*)d_in[8];
    float* out = (float*)d_out;                      // f32 output

    char* ws = (char*)d_ws;
    double* W1p = (double*)(ws);                     //   409,600 B
    double* W2p = (double*)(ws + 409600ull);         // 4,718,592 B
    double* W3p = (double*)(ws + 5128192ull);        //   524,288 B
    double* xpA = (double*)(ws + 5652480ull);        // 2,097,152 B
    double* xpB = (double*)(ws + 7749632ull);        // 2,097,152 B
    int*   modep = (int*)(ws + 9846784ull);          //       256 B
    char*  bufs = ws + 9847040ull;
    const size_t base_need = 9847040ull;
    const size_t ROWD  = 524288ull;                  // 256*256 f64 row bytes
    const size_t ROWH0 = 16384ull;                   // 256*8 f64 row bytes

    // (R, G) tier ladder — r12/r13 proven; ws in [224 MB, 276 MB) -> (64,3).
    const int cand_r[14] = {64, 128, 256, 64, 32, 64, 16, 32, 16, 8, 8, 4, 4, 2};
    const int cand_g[14] = { 4,   2,   1,  3,  4,  2,  4,  2,  2, 4, 2, 2, 1, 1};
    int R = 2, G = 1;
    for (int ci = 0; ci < 14; ++ci) {
        int r = cand_r[ci], g = cand_g[ci];
        size_t need = base_need + (size_t)g *
            ((size_t)(r + 8) * ROWH0 + (size_t)(2 * r + 6) * ROWD);
        if (ws_size >= need) { R = r; G = g; break; }
    }
    int ns_shift = 0;
    while ((256 >> ns_shift) != R) ++ns_shift;       // R=256->0 ... R=2->7
    const int NSTRIP = 256 / R;
    const int jobs = 4 * NSTRIP;

    double* h0 = (double*)bufs;
    double* h1 = (double*)(bufs + (size_t)G * (R + 8) * ROWH0);
    double* h2 = (double*)((char*)h1 + (size_t)G * (R + 4) * ROWD);
    double* h3 = h1;                                 // alias, stride h1_is
    const size_t h0_is = (size_t)(R + 8) * 256 * 8;  // element strides
    const size_t h1_is = (size_t)(R + 4) * 256 * 256;
    const size_t h2_is = (size_t)(R + 2) * 256 * 256;

    probe_mode<<<1, 64, 0, stream>>>(modep);
    repack_w1<<<200, 256, 0, stream>>>(w1, W1p);
    repack_w2<<<2304, 256, 0, stream>>>(w2, W2p);
    repack_w3<<<256, 256, 0, stream>>>(w3, W3p);
    xinit_kernel<<<NPIX / 256, 256, 0, stream>>>(x, xpA);

    for (int it = 0; it < 5; ++it) {                 // n_it = 5 (setup constant)
        const double* xp_rd = (it & 1) ? xpB : xpA;  // ping-pong: no intra-iter
        double*       xp_wr = (it & 1) ? xpA : xpB;  // RAW hazard (round 5 bug)
        for (int j0 = 0; j0 < jobs; j0 += G) {
            int g = (jobs - j0 < G) ? (jobs - j0) : G;
            stencil_strip<<<dim3(R + 8, g), 256, 0, stream>>>(
                x, xp_rd, h0, h0_is, j0, ns_shift, R);
            conv_gemm<8, 8, 5, 5><<<dim3((R + 4) * 2, 4, g), 512, 0, stream>>>(
                h0, h0_is, W1p, b1, h1, h1_is, 2, modep);
            conv2_gemm<<<dim3((R + 2) * 2, 4, g), 512, 0, stream>>>(
                h1, h1_is, W2p, b2, h2, h2_is, modep);
            conv_gemm<256, 16, 1, 1><<<dim3((R + 2) * 2, 4, g), 512, 0, stream>>>(
                h2, h2_is, W3p, b3, h3, h1_is, 0, modep);
            conv4_sig<<<dim3(R * 4, g), 256, 0, stream>>>(
                h3, h1_is, w4, b4, out, xp_wr, j0, ns_shift, R);
        }
    }
}

// Round 9
// 41981.366 us; speedup vs baseline: 1.3235x; 1.3235x over previous
//
#include <hip/hip_runtime.h>
#include <hip/hip_bf16.h>

// ---------------------------------------------------------------------------
// FULL FLOAT64 pipeline (rounds 4/5: state + activations must be f64).
// Round-23: resubmission of the proven r16/r22 kernel — round-8 bench was an
// infra failure ("container failed twice") on byte-identical source that
// already passed twice (42.0 ms, absmax 0.001953125). No kernel change.
// Model state: five structural variants measured (prod/cons 64px 42.5 |
// 8-wave 128px 42.0 best | 4-wave deep 49.2 | persistent 43.3 | write-early
// 55.6). Scheduling space exhausted; remaining lever is algorithmic
// (Winograd F(2,3) on conv2, 2.25x FLOP cut).
//
//   job j = img * NSTRIP + s ; img = j >> ns_shift ; r0 = (j & (NSTRIP-1))*R
//   h0 slot: [(R+8) rows][256][8] f64 ; h1: [(R+4)][256][256] ;
//   h2: [(R+2)][256][256] ; h3 = h1 alias
//   packed weights f64: Wp[k*256+oc], k = tap*CIN+cin (tap-major)
//   xpA/xpB: [NPIX] f64 ping-pong state; d_out: [NPIX] f32
// ---------------------------------------------------------------------------

#define NPIX (4 * 256 * 256)

typedef double v4d __attribute__((ext_vector_type(4)));

// ---------------- one-wave f64-MFMA C/D-layout probe -----------------------
__global__ __launch_bounds__(64) void probe_mode(int* __restrict__ modep)
{
    int lr = threadIdx.x & 15;
    v4d p1 = {}, p2 = {};
    p1 = __builtin_amdgcn_mfma_f64_16x16x4f64((double)lr, 1.0, p1, 0, 0, 0);
    p2 = __builtin_amdgcn_mfma_f64_16x16x4f64(1.0, (double)lr, p2, 0, 0, 0);
    double v1 = __shfl(p1[0], 16);
    double v2 = __shfl(p2[0], 16);
    if (threadIdx.x == 0)
        *modep = (v1 == 16.0) ? 0 : (v1 == 4.0) ? 1 : (v2 == 16.0) ? 2 : 3;
}

// ---------------------- x (f32) -> xp (f64) init ---------------------------
__global__ __launch_bounds__(256) void xinit_kernel(
    const float* __restrict__ x, double* __restrict__ xp64)
{
    int p = blockIdx.x * 256 + threadIdx.x;
    xp64[p] = (double)x[p];
}

// ------------------- stencil features, job-sliced --------------------------
__global__ __launch_bounds__(256) void stencil_strip(
    const float* __restrict__ x, const double* __restrict__ xp,
    double* __restrict__ h0, size_t h0_is,
    int job0, int ns_shift, int R)
{
    int slot = blockIdx.y;
    int j = job0 + slot;
    int img = j >> ns_shift;
    int r0 = (j & ((1 << ns_shift) - 1)) * R;
    int pbase = img << 16;
    int y = (r0 - 4 + blockIdx.x) & 255;
    int col = threadIdx.x;
    double q[8];
    int s = 0, idx = 0;
    #pragma unroll
    for (int i = -1; i <= 1; ++i)
        #pragma unroll
        for (int jj = -1; jj <= 1; ++jj) {
            if (i == 0 && jj == 0) continue;
            int ys = (y - i) & 255, xs = (col - jj) & 255;
            double v = xp[pbase + ((ys << 8) | xs)];
            q[idx++] = v;
            s += (v > 0.5) ? 1 : 0;
        }
    double c = xp[pbase + ((y << 8) | col)];
    bool alive = c > 0.5;
    bool binnext = (s == 3) || (alive && s == 2);
    double c0 = 1.0, c1 = 0.0, c2 = 0.0, c3 = 0.0;   // count DP, ref order
    #pragma unroll
    for (int k = 0; k < 8; ++k) {
        double qq = q[k], r = 1.0 - qq;
        c3 = c3 * r + c2 * qq;
        c2 = c2 * r + c1 * qq;
        c1 = c1 * r + c0 * qq;
        c0 = c0 * r;
    }
    double xpred = c3 + c2 * c;
    double* o = h0 + slot * h0_is + ((size_t)blockIdx.x * 256 + col) * 8;
    o[0] = (double)x[pbase + ((y << 8) | col)];
    o[1] = c;
    o[2] = alive ? 1.0 : 0.0;
    o[3] = xpred;
    o[4] = binnext ? 1.0 : 0.0;
    o[5] = 0.0; o[6] = 0.0; o[7] = 0.0;
}

// ------------- generic f64 MFMA conv GEMM (conv1/conv3) --------------------
// Tile 128px x 64oc; ALL 8 waves compute a 32x32 quadrant. Async register
// staging double-buffers LDS with one barrier per chunk. 3 blocks/CU.
template<int CIN, int TK, int KH, int KW>
__global__ __launch_bounds__(512, 6) void conv_gemm(
    const double* __restrict__ A, size_t a_is,
    const double* __restrict__ Wp,
    const float* __restrict__ bias,
    double* __restrict__ O, size_t o_is,
    int delta, const int* __restrict__ modep)
{
    constexpr int PW = KW / 2, PH = KH / 2;
    constexpr int CHUNKS = CIN / TK;
    constexpr int NCH = KH * KW * CHUNKS;
    constexpr int LPP = TK / 2;            // double2 (ch-pairs) per px
    constexpr int NA = 128 * LPP;          // A double2 tasks per chunk
    constexpr int NW = TK * 32;            // W double2 tasks per chunk
    constexpr int NT = NA + NW;
    constexpr int TPT = (NT + 511) / 512;  // staged double2 per thread

    __shared__ double Asmem[2][TK][130];   // [buf][k][px]
    __shared__ double Wsmem[2][TK][66];    // [buf][k][oc]

    const double* Ai = A + blockIdx.z * a_is;
    double* Oi = O + blockIdx.z * o_is;
    const int mode = *modep;

    const int tid = threadIdx.x;
    const int pm0 = blockIdx.x * 128;      // 128 | 256 -> row-aligned tiles
    const int on0 = blockIdx.y * 64;
    const int yl0 = pm0 >> 8;              // constant per block
    const int c0l = pm0 & 255;
    const int wave = tid >> 6, lane = tid & 63;
    const int lq = lane >> 4, lr = lane & 15;
    const int wr = (wave >> 1) * 32;       // {0,32,64,96}
    const int wc = (wave & 1) * 32;        // {0,32}

    v4d acc[2][2] = {};
    double2 st[TPT];

    auto load_tasks = [&](int ch) {
        int tap = ch / CHUNKS, cc = ch - tap * CHUNKS;
        int dy = tap / KW - PH, dx = tap % KW - PW;
        int c0 = cc * TK;
        int kglob = tap * CIN + c0;
        int srow = yl0 + dy + delta;
        #pragma unroll
        for (int i = 0; i < TPT; ++i) {
            int u = tid + i * 512;
            if (NT % 512 == 0 || u < NT) {
                if (u < NA) {
                    int px = u / LPP, pp = u % LPP;
                    int xs = (c0l + px + dx) & 255;
                    st[i] = *(const double2*)(
                        Ai + (size_t)((srow << 8) | xs) * CIN + c0 + pp * 2);
                } else {
                    int u2 = u - NA;
                    int row = u2 >> 5, cp = (u2 & 31) << 1;
                    st[i] = *(const double2*)&Wp[
                        (size_t)(kglob + row) * 256 + on0 + cp];
                }
            }
        }
    };
    auto write_tasks = [&](int buf) {
        #pragma unroll
        for (int i = 0; i < TPT; ++i) {
            int u = tid + i * 512;
            if (NT % 512 == 0 || u < NT) {
                if (u < NA) {
                    int px = u / LPP, pp = u % LPP;
                    Asmem[buf][pp * 2 + 0][px] = st[i].x;
                    Asmem[buf][pp * 2 + 1][px] = st[i].y;
                } else {
                    int u2 = u - NA;
                    int row = u2 >> 5, cp = (u2 & 31) << 1;
                    *(double2*)&Wsmem[buf][row][cp] = st[i];
                }
            }
        }
    };

    load_tasks(0);
    write_tasks(0);
    __syncthreads();
    for (int ch = 0; ch < NCH; ++ch) {
        const int cur = ch & 1;
        if (ch + 1 < NCH) load_tasks(ch + 1);   // issue early; vmcnt after MFMA
        __builtin_amdgcn_s_setprio(1);
        #pragma unroll
        for (int k0 = 0; k0 < TK / 4; ++k0) {
            const int kk = k0 * 4 + lq;
            double a[2], b[2];
            a[0] = Asmem[cur][kk][wr + lr];
            a[1] = Asmem[cur][kk][wr + 16 + lr];
            b[0] = Wsmem[cur][kk][wc + lr];
            b[1] = Wsmem[cur][kk][wc + 16 + lr];
            #pragma unroll
            for (int rt = 0; rt < 2; ++rt)
                #pragma unroll
                for (int ct = 0; ct < 2; ++ct)
                    acc[rt][ct] = __builtin_amdgcn_mfma_f64_16x16x4f64(
                        a[rt], b[ct], acc[rt][ct], 0, 0, 0);
        }
        __builtin_amdgcn_s_setprio(0);
        if (ch + 1 < NCH) write_tasks(cur ^ 1);
        __syncthreads();
    }

    #pragma unroll
    for (int rt = 0; rt < 2; ++rt)
        #pragma unroll
        for (int ct = 0; ct < 2; ++ct)
            #pragma unroll
            for (int i = 0; i < 4; ++i) {
                int hq = lq * 4 + i, hi = i * 4 + lq;
                int rl = (mode == 0) ? hq : (mode == 1) ? hi : lr;
                int cl = (mode <= 1) ? lr : (mode == 2) ? hq : hi;
                int px = pm0 + wr + rt * 16 + rl;
                int oc = on0 + wc + ct * 16 + cl;
                Oi[(size_t)px * 256 + oc] =
                    fmax(acc[rt][ct][i] + (double)bias[oc], 0.0);
            }
}

// ------------- conv2-specialized GEMM: 3x3, 256cin, dy-grouped -------------
// Chunk = (dy, cc8): A[8][130] (dx-halo over 128px), W 24 rows x 64 oc.
// ALL 8 waves compute: 24 MFMA/chunk/wave; NCH = 96. LDS 41984 B.
__global__ __launch_bounds__(512, 6) void conv2_gemm(
    const double* __restrict__ A, size_t a_is,    // h1 [R+4][256][256]
    const double* __restrict__ Wp,                // [2304, 256]
    const float* __restrict__ bias,
    double* __restrict__ O, size_t o_is,          // h2 [R+2][256][256]
    const int* __restrict__ modep)
{
    __shared__ double Asmem[2][8][130];    // [buf][k][px(-1..128)]
    __shared__ double Wsmem[2][24][66];    // [buf][dx*8+k][oc]
    constexpr int NA = 520;                // 130 px * 4 ch-pairs
    constexpr int NT = 1288;               // + 24*32 W tasks
    constexpr int TPT = 3;                 // ceil(1288/512)

    const double* Ai = A + blockIdx.z * a_is;
    double* Oi = O + blockIdx.z * o_is;
    const int mode = *modep;

    const int tid = threadIdx.x;
    const int pm0 = blockIdx.x * 128;
    const int on0 = blockIdx.y * 64;       // grid.y = 4
    const int yrow = pm0 >> 8;             // h2-local row (tile spans 1/2 row)
    const int col0 = pm0 & 255;
    const int wave = tid >> 6, lane = tid & 63;
    const int lq = lane >> 4, lr = lane & 15;
    const int wr = (wave >> 1) * 32;       // {0,32,64,96}
    const int wc = (wave & 1) * 32;        // {0,32}

    v4d acc[2][2] = {};
    double2 st[TPT];

    auto load_tasks = [&](int ch) {
        int dy = ch >> 5;                  // [0,3)
        int cc = ch & 31;
        int c0 = cc * 8;
        int srow = yrow + dy;              // h1 row (delta=1: yl+dy-1+1)
        #pragma unroll
        for (int i = 0; i < TPT; ++i) {
            int u = tid + i * 512;
            if (u < NT) {
                if (u < NA) {
                    int px = u >> 2, pp = u & 3;
                    int xs = (col0 - 1 + px) & 255;
                    st[i] = *(const double2*)(
                        Ai + (size_t)((srow << 8) | xs) * 256 + c0 + pp * 2);
                } else {
                    int u2 = u - NA;
                    int row = u2 >> 5, cp = (u2 & 31) << 1;
                    int tap = dy * 3 + (row >> 3);
                    int k = tap * 256 + c0 + (row & 7);
                    st[i] = *(const double2*)&Wp[(size_t)k * 256 + on0 + cp];
                }
            }
        }
    };
    auto write_tasks = [&](int buf) {
        #pragma unroll
        for (int i = 0; i < TPT; ++i) {
            int u = tid + i * 512;
            if (u < NT) {
                if (u < NA) {
                    int px = u >> 2, pp = u & 3;
                    Asmem[buf][pp * 2 + 0][px] = st[i].x;
                    Asmem[buf][pp * 2 + 1][px] = st[i].y;
                } else {
                    int u2 = u - NA;
                    int row = u2 >> 5, cp = (u2 & 31) << 1;
                    *(double2*)&Wsmem[buf][row][cp] = st[i];
                }
            }
        }
    };

    load_tasks(0);
    write_tasks(0);
    __syncthreads();
    for (int ch = 0; ch < 96; ++ch) {
        const int cur = ch & 1;
        if (ch + 1 < 96) load_tasks(ch + 1);    // issue early
        __builtin_amdgcn_s_setprio(1);
        #pragma unroll
        for (int dx = 0; dx < 3; ++dx)
            #pragma unroll
            for (int k0 = 0; k0 < 2; ++k0) {
                const int kA = k0 * 4 + lq;
                const int kW = dx * 8 + k0 * 4 + lq;
                double a[2], b[2];
                a[0] = Asmem[cur][kA][dx + wr + lr];
                a[1] = Asmem[cur][kA][dx + wr + 16 + lr];
                b[0] = Wsmem[cur][kW][wc + lr];
                b[1] = Wsmem[cur][kW][wc + 16 + lr];
                #pragma unroll
                for (int rt = 0; rt < 2; ++rt)
                    #pragma unroll
                    for (int ct = 0; ct < 2; ++ct)
                        acc[rt][ct] = __builtin_amdgcn_mfma_f64_16x16x4f64(
                            a[rt], b[ct], acc[rt][ct], 0, 0, 0);
            }
        __builtin_amdgcn_s_setprio(0);
        if (ch + 1 < 96) write_tasks(cur ^ 1);
        __syncthreads();
    }

    #pragma unroll
    for (int rt = 0; rt < 2; ++rt)
        #pragma unroll
        for (int ct = 0; ct < 2; ++ct)
            #pragma unroll
            for (int i = 0; i < 4; ++i) {
                int hq = lq * 4 + i, hi = i * 4 + lq;
                int rl = (mode == 0) ? hq : (mode == 1) ? hi : lr;
                int cl = (mode <= 1) ? lr : (mode == 2) ? hq : hi;
                int px = pm0 + wr + rt * 16 + rl;
                int oc = on0 + wc + ct * 16 + cl;
                Oi[(size_t)px * 256 + oc] =
                    fmax(acc[rt][ct][i] + (double)bias[oc], 0.0);
            }
}

// --------------- conv4: 256->1, 3x3, + sigmoid, wave-per-pixel -------------
__global__ __launch_bounds__(256) void conv4_sig(
    const double* __restrict__ H3, size_t h3_is,
    const float* __restrict__ w4, const float* __restrict__ b4,
    float* __restrict__ out, double* __restrict__ xp_new,
    int job0, int ns_shift, int R)
{
    __shared__ double w4s[2304];     // w4[cin][kh][kw] f64
    int tid = threadIdx.x;
    for (int i = tid; i < 2304; i += 256) w4s[i] = (double)w4[i];
    __syncthreads();
    int slot = blockIdx.y;
    int j = job0 + slot;
    int img = j >> ns_shift;
    int r0 = (j & ((1 << ns_shift) - 1)) * R;
    const double* H3i = H3 + slot * h3_is;
    int pbase = img << 16;
    int lane = tid & 63, wv = tid >> 6;
    int p0 = blockIdx.x * 64 + wv * 16;
    for (int pi = 0; pi < 16; ++pi) {
        int pl = p0 + pi;
        int yl = pl >> 8, col = pl & 255;
        double acc = 0.0;
        #pragma unroll
        for (int tap = 0; tap < 9; ++tap) {
            int row = yl + tap / 3 - 1 + 1;                 // delta = 1
            int xs = (col + tap % 3 - 1) & 255;
            const double* src = H3i + (size_t)((row << 8) | xs) * 256;
            #pragma unroll
            for (int jj = 0; jj < 4; ++jj) {
                int c = lane + 64 * jj;
                acc = fma(src[c], w4s[c * 9 + tap], acc);
            }
        }
        #pragma unroll
        for (int off = 32; off; off >>= 1) acc += __shfl_xor(acc, off, 64);
        if (lane == 0) {
            double v = acc + (double)b4[0];
            double s = 1.0 / (1.0 + exp(-v));
            int p = pbase + (((r0 + yl) << 8) | col);
            out[p] = (float)s;
            xp_new[p] = s;
        }
    }
}

// ----------------------------- weight repacks (f32 -> f64) -----------------
__global__ void repack_w1(const float* __restrict__ w1, double* __restrict__ W1p) {
    int t = blockIdx.x * 256 + threadIdx.x;           // [(tap*8+cin)*256+oc]
    if (t >= 25 * 8 * 256) return;
    int oc = t & 255, cin = (t >> 8) & 7, tap = t >> 11;
    W1p[t] = (cin < 5) ? (double)w1[oc * 125 + cin * 25 + tap] : 0.0;
}
__global__ void repack_w2(const float* __restrict__ w2, double* __restrict__ W2p) {
    int t = blockIdx.x * 256 + threadIdx.x;           // [(tap*256+cin)*256+oc]
    if (t >= 9 * 256 * 256) return;
    int oc = t & 255, cin = (t >> 8) & 255, tap = t >> 16;
    W2p[t] = (double)w2[((oc << 8) | cin) * 9 + tap];
}
__global__ void repack_w3(const float* __restrict__ w3, double* __restrict__ W3p) {
    int t = blockIdx.x * 256 + threadIdx.x;           // [cin*256+oc]
    if (t >= 256 * 256) return;
    int oc = t & 255, cin = t >> 8;
    W3p[t] = (double)w3[oc * 256 + cin];
}

// ------------------------------- launcher ----------------------------------
extern "C" void kernel_launch(void* const* d_in, const int* in_sizes, int n_in,
                              void* d_out, int out_size, void* d_ws, size_t ws_size,
                              hipStream_t stream)
{
    const float* x  = (const float*)d_in[0];
    const float* w1 = (const float*)d_in[1];
    const float* b1 = (const float*)d_in[2];
    const float* w2 = (const float*)d_in[3];
    const float* b2 = (const float*)d_in[4];
    const float* w3 = (const float*)d_in[5];
    const float* b3 = (const float*)d_in[6];
    const float* w4 = (const float*)d_in[7];
    const float* b4 = (const float*)d_in[8];
    float* out = (float*)d_out;                      // f32 output

    char* ws = (char*)d_ws;
    double* W1p = (double*)(ws);                     //   409,600 B
    double* W2p = (double*)(ws + 409600ull);         // 4,718,592 B
    double* W3p = (double*)(ws + 5128192ull);        //   524,288 B
    double* xpA = (double*)(ws + 5652480ull);        // 2,097,152 B
    double* xpB = (double*)(ws + 7749632ull);        // 2,097,152 B
    int*   modep = (int*)(ws + 9846784ull);          //       256 B
    char*  bufs = ws + 9847040ull;
    const size_t base_need = 9847040ull;
    const size_t ROWD  = 524288ull;                  // 256*256 f64 row bytes
    const size_t ROWH0 = 16384ull;                   // 256*8 f64 row bytes

    // (R, G) tier ladder — r12/r13 proven; ws in [224 MB, 276 MB) -> (64,3).
    const int cand_r[14] = {64, 128, 256, 64, 32, 64, 16, 32, 16, 8, 8, 4, 4, 2};
    const int cand_g[14] = { 4,   2,   1,  3,  4,  2,  4,  2,  2, 4, 2, 2, 1, 1};
    int R = 2, G = 1;
    for (int ci = 0; ci < 14; ++ci) {
        int r = cand_r[ci], g = cand_g[ci];
        size_t need = base_need + (size_t)g *
            ((size_t)(r + 8) * ROWH0 + (size_t)(2 * r + 6) * ROWD);
        if (ws_size >= need) { R = r; G = g; break; }
    }
    int ns_shift = 0;
    while ((256 >> ns_shift) != R) ++ns_shift;       // R=256->0 ... R=2->7
    const int NSTRIP = 256 / R;
    const int jobs = 4 * NSTRIP;

    double* h0 = (double*)bufs;
    double* h1 = (double*)(bufs + (size_t)G * (R + 8) * ROWH0);
    double* h2 = (double*)((char*)h1 + (size_t)G * (R + 4) * ROWD);
    double* h3 = h1;                                 // alias, stride h1_is
    const size_t h0_is = (size_t)(R + 8) * 256 * 8;  // element strides
    const size_t h1_is = (size_t)(R + 4) * 256 * 256;
    const size_t h2_is = (size_t)(R + 2) * 256 * 256;

    probe_mode<<<1, 64, 0, stream>>>(modep);
    repack_w1<<<200, 256, 0, stream>>>(w1, W1p);
    repack_w2<<<2304, 256, 0, stream>>>(w2, W2p);
    repack_w3<<<256, 256, 0, stream>>>(w3, W3p);
    xinit_kernel<<<NPIX / 256, 256, 0, stream>>>(x, xpA);

    for (int it = 0; it < 5; ++it) {                 // n_it = 5 (setup constant)
        const double* xp_rd = (it & 1) ? xpB : xpA;  // ping-pong: no intra-iter
        double*       xp_wr = (it & 1) ? xpA : xpB;  // RAW hazard (round 5 bug)
        for (int j0 = 0; j0 < jobs; j0 += G) {
            int g = (jobs - j0 < G) ? (jobs - j0) : G;
            stencil_strip<<<dim3(R + 8, g), 256, 0, stream>>>(
                x, xp_rd, h0, h0_is, j0, ns_shift, R);
            conv_gemm<8, 8, 5, 5><<<dim3((R + 4) * 2, 4, g), 512, 0, stream>>>(
                h0, h0_is, W1p, b1, h1, h1_is, 2, modep);
            conv2_gemm<<<dim3((R + 2) * 2, 4, g), 512, 0, stream>>>(
                h1, h1_is, W2p, b2, h2, h2_is, modep);
            conv_gemm<256, 16, 1, 1><<<dim3((R + 2) * 2, 4, g), 512, 0, stream>>>(
                h2, h2_is, W3p, b3, h3, h1_is, 0, modep);
            conv4_sig<<<dim3(R * 4, g), 256, 0, stream>>>(
                h3, h1_is, w4, b4, out, xp_wr, j0, ns_shift, R);
        }
    }
}